// Round 1
// baseline (758.076 us; speedup 1.0000x reference)
//
#include <hip/hip_runtime.h>

// MLMM electrostatics: per-pair energy -> scatter-add onto ML atoms.
// Inputs (float32 unless noted):
//  0 atomic_charges      [NML]
//  1 mm_atomic_charges   [NMM]
//  2 atomic_dipoles      [NML,3]
//  3 atomic_quadrupoles  [NML,3,3]
//  4 atomic_energies     [NML]
//  5 mlmm_distances_uv   [P]
//  6 mlmm_vectors_uv     [P,3]
//  7 mlmm_outer_product_uv [P,3,3]
//  8 mlmm_idx_u          [P] int32
//  9 mlmm_idx_v          [P] int32
// out: atomic_energies + segment_sum(Eelec, idx_u)   [NML] float32

static constexpr float KE_F     = 14.399645351950548f;
static constexpr float CUTOFF_F = 10.0f;

__global__ void init_out_kernel(const float* __restrict__ energies,
                                float* __restrict__ out, int n) {
    int i = blockIdx.x * blockDim.x + threadIdx.x;
    if (i < n) out[i] = energies[i];
}

__device__ __forceinline__ void pair_contrib(
    float di, int ui, int vi,
    const float* __restrict__ vp,   // 3 floats: pair vector
    const float* __restrict__ op,   // 9 floats: pair outer product
    const float* __restrict__ q_ml,
    const float* __restrict__ q_mm,
    const float* __restrict__ mu,   // [NML,3]
    const float* __restrict__ Q,    // [NML,9]
    float* __restrict__ out)
{
    if (di > CUTOFF_F) return;          // masked pair: no load of tables, no atomic
    float chi  = 1.0f / di;
    float chi2 = chi * chi;
    float chi3 = chi2 * chi;
    float chi5 = chi3 * chi2;

    float qu = q_ml[ui];
    float qv = q_mm[vi];

    const float* m = mu + 3 * ui;
    float dot = vp[0]*m[0] + vp[1]*m[1] + vp[2]*m[2];

    const float* qq = Q + 9 * ui;
    float S = op[0]*qq[0] + op[1]*qq[1] + op[2]*qq[2]
            + op[3]*qq[3] + op[4]*qq[4] + op[5]*qq[5]
            + op[6]*qq[6] + op[7]*qq[7] + op[8]*qq[8];
    float dm  = (op[0] + op[4] + op[8]) * (1.0f / 3.0f);
    float trQ = qq[0] + qq[4] + qq[8];

    // E = KE * q_v * ( q_u*chi - chi3*(vec.mu) + chi5*(S - dm*trQ) )
    float E = KE_F * qv * (qu * chi - chi3 * dot + chi5 * (S - dm * trQ));
    atomicAdd(out + ui, E);
}

__global__ __launch_bounds__(256) void mlmm_pair_kernel(
    const float* __restrict__ q_ml,
    const float* __restrict__ q_mm,
    const float* __restrict__ mu,
    const float* __restrict__ Q,
    const float* __restrict__ dist,
    const float* __restrict__ vec,
    const float* __restrict__ outer,
    const int*   __restrict__ idx_u,
    const int*   __restrict__ idx_v,
    float* __restrict__ out,
    int n4, int npairs)
{
    int t = blockIdx.x * blockDim.x + threadIdx.x;

    if (t < n4) {
        // ---- fully aligned 16B staging of 4 consecutive pairs ----
        const float4* d4  = (const float4*)dist;   // 1 x float4
        const int4*   iu4 = (const int4*)idx_u;    // 1 x int4
        const int4*   iv4 = (const int4*)idx_v;    // 1 x int4
        const float4* v4  = (const float4*)vec;    // 3 x float4 (12 floats)
        const float4* o4  = (const float4*)outer;  // 9 x float4 (36 floats, 144B)

        float4 d  = d4[t];
        int4   u  = iu4[t];
        int4   v  = iv4[t];

        float4 vv[3];
        #pragma unroll
        for (int k = 0; k < 3; ++k) vv[k] = v4[3 * t + k];
        float4 oo[9];
        #pragma unroll
        for (int k = 0; k < 9; ++k) oo[k] = o4[9 * t + k];

        const float* vf = (const float*)vv;  // 12 floats = 4 pairs x 3
        const float* of = (const float*)oo;  // 36 floats = 4 pairs x 9
        float dd[4] = {d.x, d.y, d.z, d.w};
        int   uu[4] = {u.x, u.y, u.z, u.w};
        int   wv[4] = {v.x, v.y, v.z, v.w};

        #pragma unroll
        for (int p = 0; p < 4; ++p) {
            pair_contrib(dd[p], uu[p], wv[p], vf + 3 * p, of + 9 * p,
                         q_ml, q_mm, mu, Q, out);
        }
    }

    // ---- tail (P not multiple of 4): handled by first threads of block 0 ----
    int tail = npairs - 4 * n4;
    if (blockIdx.x == 0 && (int)threadIdx.x < tail) {
        int i = 4 * n4 + threadIdx.x;
        pair_contrib(dist[i], idx_u[i], idx_v[i],
                     vec + 3 * i, outer + 9 * i,
                     q_ml, q_mm, mu, Q, out);
    }
}

extern "C" void kernel_launch(void* const* d_in, const int* in_sizes, int n_in,
                              void* d_out, int out_size, void* d_ws, size_t ws_size,
                              hipStream_t stream) {
    const float* q_ml   = (const float*)d_in[0];
    const float* q_mm   = (const float*)d_in[1];
    const float* mu     = (const float*)d_in[2];
    const float* Q      = (const float*)d_in[3];
    const float* ene    = (const float*)d_in[4];
    const float* dist   = (const float*)d_in[5];
    const float* vec    = (const float*)d_in[6];
    const float* outer  = (const float*)d_in[7];
    const int*   idx_u  = (const int*)d_in[8];
    const int*   idx_v  = (const int*)d_in[9];
    float* out = (float*)d_out;

    int nml    = in_sizes[4];   // NML
    int npairs = in_sizes[5];   // P
    int n4     = npairs >> 2;

    // 1) out = atomic_energies  (d_out is poisoned before every call)
    {
        int threads = 256;
        int blocks = (nml + threads - 1) / threads;
        init_out_kernel<<<blocks, threads, 0, stream>>>(ene, out, nml);
    }
    // 2) pair energies + scatter atomics (same stream -> ordered after init)
    {
        int threads = 256;
        int blocks = (n4 + threads - 1) / threads;
        if (blocks < 1) blocks = 1;
        mlmm_pair_kernel<<<blocks, threads, 0, stream>>>(
            q_ml, q_mm, mu, Q, dist, vec, outer, idx_u, idx_v, out, n4, npairs);
    }
}